// Round 9
// baseline (109.137 us; speedup 1.0000x reference)
//
#include <hip/hip_runtime.h>

#define C 128
#define H 128
#define W 128
#define HW (H*W)

// K0: transpose feat [B][C][H][W] -> T [B][H][C][W] so the compute kernel's
// channel loop walks contiguous 512B rows (kills the 64KB power-of-2 stride).
__global__ __launch_bounds__(512) void transpose_kernel(
    const float* __restrict__ feat, float* __restrict__ T)
{
    const int blk  = blockIdx.x;       // b*H + r
    const int b    = blk >> 7;
    const int r    = blk & 127;
    const int tid  = threadIdx.x;
    const int wv   = tid >> 6;         // 0..7
    const int lane = tid & 63;
    const int q    = lane & 31;        // float4 slot within the 512B row
    const int ch0  = wv * 2 + (lane >> 5);
#pragma unroll
    for (int k = 0; k < 8; ++k) {
        const int c = k * 16 + ch0;
        const float4 v = *(const float4*)(feat + ((size_t)(b * C + c) * H + r) * W + q * 4);
        *(float4*)(T + ((size_t)(b * H + r) * C + c) * W + q * 4) = v;
    }
}

// K1: fused corr(25 dilated taps) + g + relu + softmax + gather + bias, on T.
// block = (b, output row r), 640 thr = 10 waves = (tap-row ti) x (ch-half h).
// lane: s = lane>>5 -> 32-ch subgroup, pg = lane&31 -> 4 px; halo via shuffles.
__global__ __launch_bounds__(640, 5) void fused_kernel(
    const float* __restrict__ T, const float* __restrict__ wc,
    const float* __restrict__ bc, float* __restrict__ out)
{
    __shared__ float corr_s[2][25][W];   // [ch-half][tap][col]
    __shared__ float g_s[2][5][W];       // [ch-half][tap-row][col]
    __shared__ float wc_s[C];

    const int blk0 = blockIdx.x;
    const int blk  = (blk0 & 7) * 64 + (blk0 >> 3);   // XCD swizzle (512 = 8*64)
    const int b    = blk >> 7;
    const int r    = blk & 127;
    const int tid  = threadIdx.x;
    const int wv   = tid >> 6;           // 0..9
    const int ti   = wv >> 1;            // tap-row index 0..4
    const int h    = wv & 1;             // 64-channel half
    const int lane = tid & 63;
    const int s    = lane >> 5;          // 32-channel subgroup
    const int pg   = lane & 31;
    const int w0   = pg * 4;             // lane owns cols w0..w0+3

    if (tid < C) wc_s[tid] = wc[tid];
    __syncthreads();

    const int  rt  = r - 4 + 2 * ti;     // wave's tap row
    const bool rok = (unsigned)rt < (unsigned)H;

    float acc[5][4];                     // corr partials, taps (ti, j) x 4 px
    float ga[4];                         // g partial for row rt
#pragma unroll
    for (int j = 0; j < 5; ++j)
#pragma unroll
        for (int p = 0; p < 4; ++p) acc[j][p] = 0.f;
#pragma unroll
    for (int p = 0; p < 4; ++p) ga[p] = 0.f;

    if (rok) {                           // wave-uniform
        const int cbase = h * 64 + s * 32;
        const float* tp = T + ((size_t)(b * H + rt) * C + cbase) * W + w0;  // tap rows
        const float* cp = T + ((size_t)(b * H + r ) * C + cbase) * W + w0;  // center rows
        const bool isCtr = (ti == 2);

#pragma unroll 1
        for (int cc = 0; cc < 32; cc += 4) {
            float4 Tv[4], Dv[4];
#pragma unroll
            for (int u = 0; u < 4; ++u)
                Tv[u] = *(const float4*)(tp + (cc + u) * W);   // +512B per channel
            if (isCtr) {
#pragma unroll
                for (int u = 0; u < 4; ++u) Dv[u] = Tv[u];
            } else {
#pragma unroll
                for (int u = 0; u < 4; ++u)
                    Dv[u] = *(const float4*)(cp + (cc + u) * W);
            }
#pragma unroll
            for (int u = 0; u < 4; ++u) {
                const float wcv = wc_s[cbase + cc + u];
                const float ctr[4] = {Dv[u].x, Dv[u].y, Dv[u].z, Dv[u].w};
                // window rel cols -4..7 -> win[0..11]; tap (j,p) uses win[p+2j]
                float win[12];
                win[4] = Tv[u].x; win[5] = Tv[u].y; win[6] = Tv[u].z; win[7] = Tv[u].w;
                win[0]  = __shfl_up(Tv[u].x, 1);   // pg==0 garbage -> cols<0, masked
                win[1]  = __shfl_up(Tv[u].y, 1);
                win[2]  = __shfl_up(Tv[u].z, 1);
                win[3]  = __shfl_up(Tv[u].w, 1);
                win[8]  = __shfl_down(Tv[u].x, 1); // pg==31 garbage -> cols>=W, masked
                win[9]  = __shfl_down(Tv[u].y, 1);
                win[10] = __shfl_down(Tv[u].z, 1);
                win[11] = __shfl_down(Tv[u].w, 1);
#pragma unroll
                for (int p = 0; p < 4; ++p)
                    ga[p] = fmaf(wcv, win[4 + p], ga[p]);
#pragma unroll
                for (int p = 0; p < 4; ++p)
                    acc[2][p] = fmaf(ctr[p], win[4 + p], acc[2][p]);
#pragma unroll
                for (int j = 0; j < 5; ++j) {
                    if (j == 2) continue;
#pragma unroll
                    for (int p = 0; p < 4; ++p)
                        acc[j][p] = fmaf(ctr[p], win[p + 2 * j], acc[j][p]);
                }
            }
        }
    }

    // reduce the two 32-channel subgroups within the wave
#pragma unroll
    for (int j = 0; j < 5; ++j)
#pragma unroll
        for (int p = 0; p < 4; ++p)
            acc[j][p] += __shfl_xor(acc[j][p], 32);
#pragma unroll
    for (int p = 0; p < 4; ++p) ga[p] += __shfl_xor(ga[p], 32);

    // masked disjoint writes (s==0 lanes cover all 128 cols)
    if (s == 0) {
#pragma unroll
        for (int j = 0; j < 5; ++j)
#pragma unroll
            for (int p = 0; p < 4; ++p) {
                const int  col = w0 + p - 4 + 2 * j;
                const bool ok  = rok && ((unsigned)col < (unsigned)W);
                corr_s[h][ti * 5 + j][w0 + p] = ok ? acc[j][p] : 0.f;
            }
#pragma unroll
        for (int p = 0; p < 4; ++p) g_s[h][ti][w0 + p] = ga[p];  // 0 if !rok
    }
    __syncthreads();

    // relu -> softmax over 25 taps -> sum attn * g -> + bias
    if (tid < W) {
        const int w = tid;
        float v[25], m = 0.f;
#pragma unroll
        for (int n = 0; n < 25; ++n) {
            v[n] = fmaxf(corr_s[0][n][w] + corr_s[1][n][w], 0.f);
            m = fmaxf(m, v[n]);
        }
        float sum = 0.f, num = 0.f;
#pragma unroll
        for (int i = 0; i < 5; ++i) {
            const bool riv = (unsigned)(r - 4 + 2 * i) < (unsigned)H;
#pragma unroll
            for (int j = 0; j < 5; ++j) {
                const float e = __expf(v[i * 5 + j] - m);
                sum += e;
                const int  wt = w - 4 + 2 * j;
                const bool ok = riv && ((unsigned)wt < (unsigned)W);
                const int  wi = ok ? wt : 0;
                const float gv = g_s[0][i][wi] + g_s[1][i][wi];
                num = fmaf(e, ok ? gv : 0.f, num);
            }
        }
        out[((size_t)(b * H + r)) * W + w] = num / sum + bc[0];
    }
}

extern "C" void kernel_launch(void* const* d_in, const int* in_sizes, int n_in,
                              void* d_out, int out_size, void* d_ws, size_t ws_size,
                              hipStream_t stream) {
    const float* feat = (const float*)d_in[0];
    const float* wcls = (const float*)d_in[1];
    const float* bcls = (const float*)d_in[2];
    float* outp = (float*)d_out;
    float* T    = (float*)d_ws;        // 4*128*128*128 floats = 33.5 MB scratch

    transpose_kernel<<<dim3(4 * H), dim3(512), 0, stream>>>(feat, T);
    fused_kernel<<<dim3(4 * H), dim3(640), 0, stream>>>(T, wcls, bcls, outp);
}

// Round 10
// 101.941 us; speedup vs baseline: 1.0706x; 1.0706x over previous
//
#include <hip/hip_runtime.h>

#define C 128
#define H 128
#define W 128
#define HW (H*W)

// K1: corr partials for 25 dilated taps + g(=feat·w_cls) partial, per (b,r,ch-half).
// 640 thr = 10 waves = (tap-row ti 0..4) x (32-ch quarter q). lane: s=16-ch subgroup,
// pg = 4-px group (float4). Small live set (<=64 VGPR, launch_bounds(640,8)).
__global__ __launch_bounds__(640, 8) void corr_kernel(
    const float* __restrict__ feat, const float* __restrict__ wc,
    float* __restrict__ corrG, float* __restrict__ gG)
{
    __shared__ float corr_s[2][25][W];   // [q][tap][col]
    __shared__ float g_s[2][W];          // [q][col]

    const int blk0 = blockIdx.x;
    const int blk  = (blk0 & 7) * 128 + (blk0 >> 3);  // XCD swizzle (1024 = 8*128)
    const int b    = blk >> 8;           // 0..3
    const int r    = (blk >> 1) & 127;   // output row
    const int h    = blk & 1;            // channel half
    const int tid  = threadIdx.x;
    const int wv   = tid >> 6;           // 0..9
    const int ti   = wv >> 1;            // tap-row index 0..4
    const int q    = wv & 1;             // 32-ch quarter within the half
    const int lane = tid & 63;
    const int s    = lane >> 5;          // 16-ch subgroup
    const int pg   = lane & 31;
    const int w0   = pg * 4;             // lane owns cols w0..w0+3

    const int  rt  = r - 4 + 2 * ti;     // wave's tap row
    const bool rok = (unsigned)rt < (unsigned)H;

    float acc[5][4];
    float ga[4] = {0.f, 0.f, 0.f, 0.f};
#pragma unroll
    for (int j = 0; j < 5; ++j)
#pragma unroll
        for (int p = 0; p < 4; ++p) acc[j][p] = 0.f;

    if (rok) {                           // wave-uniform
        // window slots: floats [w0-4, w0+8) as 3 aligned float4; clamped slot
        // => all its taps provably OOB => masked below.
        int sb[3];
#pragma unroll
        for (int t = 0; t < 3; ++t) {
            const int cs = w0 - 4 + 4 * t;
            sb[t] = cs < 0 ? 0 : (cs > W - 4 ? W - 4 : cs);
        }
        const int cbase = h * 64 + q * 32 + s * 16;
        const float* tp = feat + ((size_t)(b * C + cbase) * H + rt) * W;
        const float* cp = feat + ((size_t)(b * C + cbase) * H + r ) * W + w0;
        const bool isCtr = (ti == 2);

#pragma unroll 1
        for (int c = 0; c < 16; ++c) {
            const float4 A  = *(const float4*)(tp + sb[0]);
            const float4 Bv = *(const float4*)(tp + sb[1]);
            const float4 Cv = *(const float4*)(tp + sb[2]);
            float4 D;
            if (isCtr) D = Bv;           // tap row == center row
            else       D = *(const float4*)cp;
            const float wcv = wc[cbase + c];   // wave-uniform -> s_load
            const float win[12] = {A.x, A.y, A.z, A.w,
                                   Bv.x, Bv.y, Bv.z, Bv.w,
                                   Cv.x, Cv.y, Cv.z, Cv.w};
            const float ctr[4] = {D.x, D.y, D.z, D.w};
            if (isCtr) {
#pragma unroll
                for (int p = 0; p < 4; ++p)
                    ga[p] = fmaf(wcv, win[4 + p], ga[p]);
            }
#pragma unroll
            for (int j = 0; j < 5; ++j)
#pragma unroll
                for (int p = 0; p < 4; ++p)
                    acc[j][p] = fmaf(ctr[p], win[p + 2 * j], acc[j][p]);
            tp += HW; cp += HW;
        }
    }

    // combine the two 16-ch subgroups within the wave
#pragma unroll
    for (int j = 0; j < 5; ++j)
#pragma unroll
        for (int p = 0; p < 4; ++p)
            acc[j][p] += __shfl_xor(acc[j][p], 32);
    if (ti == 2) {
#pragma unroll
        for (int p = 0; p < 4; ++p) ga[p] += __shfl_xor(ga[p], 32);
    }

    // disjoint LDS writes (s==0 lanes cover all 128 cols); masked -> exact zero-pad
    if (s == 0) {
#pragma unroll
        for (int j = 0; j < 5; ++j)
#pragma unroll
            for (int p = 0; p < 4; ++p) {
                const int  col = w0 + p - 4 + 2 * j;
                const bool ok  = rok && ((unsigned)col < (unsigned)W);
                corr_s[q][ti * 5 + j][w0 + p] = ok ? acc[j][p] : 0.f;
            }
        if (ti == 2) {
#pragma unroll
            for (int p = 0; p < 4; ++p) g_s[q][w0 + p] = ga[p];
        }
    }
    __syncthreads();

    // store combined partials (coalesced)
    float* cg = corrG + (size_t)blk * (25 * W);
    const float* s0 = &corr_s[0][0][0];
    const float* s1 = &corr_s[1][0][0];
    for (int idx = tid; idx < 25 * W; idx += 640)
        cg[idx] = s0[idx] + s1[idx];
    if (tid < W)
        gG[(size_t)blk * W + tid] = g_s[0][tid] + g_s[1][tid];
}

// K2: relu -> softmax over 25 taps -> sum attn*g -> + bias. XCD-matched to K1.
__global__ __launch_bounds__(128) void soft_kernel(
    const float* __restrict__ corrG, const float* __restrict__ gG,
    const float* __restrict__ bc, float* __restrict__ out)
{
    const int blk0 = blockIdx.x;
    const int xcd  = blk0 & 7;
    const int idx  = blk0 >> 3;
    const int b    = xcd >> 1;                 // matches K1's XCD(b,r) = 2b + (r>>6)
    const int r    = (xcd & 1) * 64 + idx;
    const int w    = threadIdx.x;

    const size_t base = ((size_t)(b * H + r)) * 2;     // K1 blk id for h=0
    const float* c0 = corrG + base * (25 * W);
    const float* c1 = c0 + (25 * W);

    float v[25], m = 0.f;
#pragma unroll
    for (int n = 0; n < 25; ++n) {
        v[n] = fmaxf(c0[n * W + w] + c1[n * W + w], 0.f);
        m = fmaxf(m, v[n]);
    }
    float sum = 0.f, num = 0.f;
#pragma unroll
    for (int i = 0; i < 5; ++i) {
        const int  rt  = r - 4 + 2 * i;
        const bool riv = (unsigned)rt < (unsigned)H;
        const size_t gb = ((size_t)(b * H + (riv ? rt : 0))) * 2 * W;
#pragma unroll
        for (int j = 0; j < 5; ++j) {
            const float e = __expf(v[i * 5 + j] - m);
            sum += e;
            const int  wt = w - 4 + 2 * j;
            const bool ok = riv && ((unsigned)wt < (unsigned)W);
            const int  wi = ok ? wt : 0;
            const float gv = gG[gb + wi] + gG[gb + W + wi];
            num = fmaf(e, ok ? gv : 0.f, num);
        }
    }
    out[((size_t)(b * H + r)) * W + w] = num / sum + bc[0];
}

extern "C" void kernel_launch(void* const* d_in, const int* in_sizes, int n_in,
                              void* d_out, int out_size, void* d_ws, size_t ws_size,
                              hipStream_t stream) {
    const float* feat = (const float*)d_in[0];
    const float* wcls = (const float*)d_in[1];
    const float* bcls = (const float*)d_in[2];
    float* outp  = (float*)d_out;
    float* corrG = (float*)d_ws;                       // 1024*3200*4 = 13.1 MB
    float* gG    = corrG + (size_t)1024 * 25 * W;      // 1024*128*4  = 0.5 MB

    corr_kernel<<<dim3(1024), dim3(640), 0, stream>>>(feat, wcls, corrG, gG);
    soft_kernel<<<dim3(512), dim3(128), 0, stream>>>(corrG, gG, bcls, outp);
}